// Round 9
// baseline (80.798 us; speedup 1.0000x reference)
//
#include <hip/hip_runtime.h>

// TreeRecurrentTagger: B=32, N=1023 nodes (complete heap), HID=128, NCLS=2.
// 3 stream-ordered kernels. Weights in per-thread registers, activations in
// LDS, fp32 VALU.
//
// R3: fit under the RA's 128-VGPR occupancy target. 1853 -> 142.6 µs.
// R4: readlane broadcast — regressed (175): broadcast ds_read is free. Revert.
// R5: granule-interleaved k-split + shfl_xor reduce. 142.6 -> 100.2 µs.
// R6/R7: R=4 rows/thread KS=16 (4x fewer ds_read) + complete 16-lane fold.
//        100.2 -> 80.6 µs.
// R8: kC processes 2 subtrees per block (grid 512 -> 256 = 1 block/CU, one
//     resident round). Weight regs + wcl staged once, reused; halves kC's
//     Wd re-fetch traffic and removes the 2nd block-scheduling round.

constexpr int NNODES = 1023;
constexpr int HB = 128;   // HID

// ---- folding cross-lane reduces within 16-lane groups ----
// a[NV] per-lane partials; every value needs the sum over ALL 16 lanes.
// fold16 alone is complete; fold8/fold4 need the extra xor stages (foldCH).
__device__ __forceinline__ float fold16(const float* a, int l) {
  float b[8];
#pragma unroll
  for (int u = 0; u < 8; ++u) {
    const float mine = (l & 1) ? a[2 * u + 1] : a[2 * u];
    const float oth  = (l & 1) ? a[2 * u]     : a[2 * u + 1];
    b[u] = mine + __shfl_xor(oth, 1);
  }
  float c[4];
#pragma unroll
  for (int u = 0; u < 4; ++u) {
    const float mine = (l & 2) ? b[2 * u + 1] : b[2 * u];
    const float oth  = (l & 2) ? b[2 * u]     : b[2 * u + 1];
    c[u] = mine + __shfl_xor(oth, 2);
  }
  float d[2];
#pragma unroll
  for (int u = 0; u < 2; ++u) {
    const float mine = (l & 4) ? c[2 * u + 1] : c[2 * u];
    const float oth  = (l & 4) ? c[2 * u]     : c[2 * u + 1];
    d[u] = mine + __shfl_xor(oth, 4);
  }
  const float mine = (l & 8) ? d[1] : d[0];
  const float oth  = (l & 8) ? d[0] : d[1];
  return mine + __shfl_xor(oth, 8);
}

__device__ __forceinline__ float fold8(const float* a, int l) {
  float b[4];
#pragma unroll
  for (int u = 0; u < 4; ++u) {
    const float mine = (l & 1) ? a[2 * u + 1] : a[2 * u];
    const float oth  = (l & 1) ? a[2 * u]     : a[2 * u + 1];
    b[u] = mine + __shfl_xor(oth, 1);
  }
  float c[2];
#pragma unroll
  for (int u = 0; u < 2; ++u) {
    const float mine = (l & 2) ? b[2 * u + 1] : b[2 * u];
    const float oth  = (l & 2) ? b[2 * u]     : b[2 * u + 1];
    c[u] = mine + __shfl_xor(oth, 2);
  }
  const float mine = (l & 4) ? c[1] : c[0];
  const float oth  = (l & 4) ? c[0] : c[1];
  return mine + __shfl_xor(oth, 4);
}

__device__ __forceinline__ float fold4(const float* a, int l) {
  float b[2];
#pragma unroll
  for (int u = 0; u < 2; ++u) {
    const float mine = (l & 1) ? a[2 * u + 1] : a[2 * u];
    const float oth  = (l & 1) ? a[2 * u]     : a[2 * u + 1];
    b[u] = mine + __shfl_xor(oth, 1);
  }
  const float mine = (l & 2) ? b[1] : b[0];
  const float oth  = (l & 2) ? b[0] : b[1];
  return mine + __shfl_xor(oth, 2);
}

// Complete 16-lane total for value v = l16 & (CH*4-1), landing on lane v
// (and its duplicates at v+CH*4, ...).
template<int CH>
__device__ __forceinline__ float foldCH(const float (&a)[CH * 4], int l16) {
  if constexpr (CH == 4) {
    return fold16(a, l16);
  } else if constexpr (CH == 2) {
    float t = fold8(a, l16);
    t += __shfl_xor(t, 8);             // other 8-lane half, same value index
    return t;
  } else {
    float t = fold4(a, l16);
    t += __shfl_xor(t, 4);             // complete the 16-lane sum
    t += __shfl_xor(t, 8);
    return t;
  }
}

// ---------- up pass: CH parents, out = tanh(Wc @ [h_l, h_r] + bc) ----------
// Thread: row-group g (rows 4g..4g+3), k-lane l16 (k-slice = floats
// l16*4 + 64m + e, m=0..3 of the 256-wide child ctx at node cb+2p).
// w[r][m] = Wc row 4g+r, that k-slice. bias_r = bc[4g + (l16&3)].
template<int CH>
__device__ __forceinline__ void up_pass(float* __restrict__ heap, int base, int cb,
                                        int cbase, const float4 (&w)[4][4],
                                        float bias_r, int g, int l16, bool wr) {
  float a[CH * 4];
#pragma unroll
  for (int v = 0; v < CH * 4; ++v) a[v] = 0.f;
#pragma unroll
  for (int p = 0; p < CH; ++p) {
    const float* cp = heap + (cb + 2 * (cbase + p)) * HB + l16 * 4;
#pragma unroll
    for (int m = 0; m < 4; ++m) {
      const float4 cc = *(const float4*)(cp + m * 64);
#pragma unroll
      for (int r = 0; r < 4; ++r) {
        const float4 wv = w[r][m];
        a[p * 4 + r] = fmaf(wv.x, cc.x, fmaf(wv.y, cc.y,
                        fmaf(wv.z, cc.z, fmaf(wv.w, cc.w, a[p * 4 + r]))));
      }
    }
  }
  const float tot = foldCH<CH>(a, l16);
  if (wr && l16 < CH * 4) {
    const int p = l16 >> 2;
    heap[(base + cbase + p) * HB + 4 * g + (l16 & 3)] = tanhf(tot + bias_r);
  }
}

// NH = thread-halves (1: all threads share parents; 2: halves take disjoint parents).
template<int NP, int NH>
__device__ __forceinline__ void up_level16(float* __restrict__ heap,
                                           const float4 (&w)[4][4],
                                           float bias_r, int g, int l16, int ph) {
  constexpr int base = NP - 1, cb = 2 * NP - 1;
  if constexpr (NP >= 4 * NH) {
#pragma unroll
    for (int c0 = 0; c0 < NP; c0 += 4 * NH)
      up_pass<4>(heap, base, cb, c0 + ph * 4, w, bias_r, g, l16, true);
  } else if constexpr (NP * 2 == 4 * NH) {
    up_pass<2>(heap, base, cb, ph * 2, w, bias_r, g, l16, true);
  } else if constexpr (NP == NH) {
    up_pass<1>(heap, base, cb, ph, w, bias_r, g, l16, true);
  } else {  // NP=1, NH=2: both halves compute, half 0 writes
    up_pass<1>(heap, base, cb, 0, w, bias_r, g, l16, ph == 0);
  }
  __syncthreads();
}

// ---------- down pass: ch = tanh(Wd @ [down_p, up_p] + bd) ----------
// ctx k: m=0,1 -> down[l16*4 + 64m]; m=2,3 -> up[l16*4 + 64(m-2)].
// Lane l16 writes (parent cbase+(l16>>2), output row 4g+(l16&3)); row<128 ->
// left child, else right.
template<int CH>
__device__ __forceinline__ void down_pass(float* __restrict__ db,
                                          const float* __restrict__ ub,
                                          int base, int cb, int cbase,
                                          const float4 (&w)[4][4],
                                          float bias_r, int g, int l16) {
  float a[CH * 4];
#pragma unroll
  for (int v = 0; v < CH * 4; ++v) a[v] = 0.f;
#pragma unroll
  for (int p = 0; p < CH; ++p) {
    const float* dp = db + (base + cbase + p) * HB + l16 * 4;
    const float* up = ub + (base + cbase + p) * HB + l16 * 4;
#pragma unroll
    for (int m = 0; m < 4; ++m) {
      const float4 cc = *(const float4*)(((m < 2) ? dp : up) + (m & 1) * 64);
#pragma unroll
      for (int r = 0; r < 4; ++r) {
        const float4 wv = w[r][m];
        a[p * 4 + r] = fmaf(wv.x, cc.x, fmaf(wv.y, cc.y,
                        fmaf(wv.z, cc.z, fmaf(wv.w, cc.w, a[p * 4 + r]))));
      }
    }
  }
  const float tot = foldCH<CH>(a, l16);
  if (l16 < CH * 4) {
    const int p = l16 >> 2;
    const int row = 4 * g + (l16 & 3);     // 0..255
    db[(cb + 2 * (cbase + p) + (row >> 7)) * HB + (row & 127)] = tanhf(tot + bias_r);
  }
}

template<int NP>
__device__ __forceinline__ void down_level16(float* __restrict__ db,
                                             const float* __restrict__ ub,
                                             const float4 (&w)[4][4],
                                             float bias_r, int g, int l16) {
  constexpr int base = NP - 1, cb = 2 * NP - 1;
  if constexpr (NP >= 4) {
#pragma unroll
    for (int c0 = 0; c0 < NP; c0 += 4)
      down_pass<4>(db, ub, base, cb, c0, w, bias_r, g, l16);
  } else {
    down_pass<NP>(db, ub, base, cb, 0, w, bias_r, g, l16);
  }
  __syncthreads();
}

// ---------- classifier, 16 threads/node, float4 loads + shfl reduce ----------
__device__ __forceinline__ void classify16(const float* __restrict__ dn,
                                           const float* __restrict__ un,
                                           const float* __restrict__ wcl,
                                           const float* __restrict__ bcl,
                                           float* __restrict__ o, int l16) {
  const int k0 = l16 * 8;
  float s0, s1;
  {
    const float4 d0 = *(const float4*)(dn + k0);
    const float4 d1 = *(const float4*)(dn + k0 + 4);
    const float4 a0 = *(const float4*)(wcl + k0);
    const float4 a1 = *(const float4*)(wcl + k0 + 4);
    const float4 b0 = *(const float4*)(wcl + 256 + k0);
    const float4 b1 = *(const float4*)(wcl + 256 + k0 + 4);
    s0 = d0.x * a0.x + d0.y * a0.y + d0.z * a0.z + d0.w * a0.w
       + d1.x * a1.x + d1.y * a1.y + d1.z * a1.z + d1.w * a1.w;
    s1 = d0.x * b0.x + d0.y * b0.y + d0.z * b0.z + d0.w * b0.w
       + d1.x * b1.x + d1.y * b1.y + d1.z * b1.z + d1.w * b1.w;
  }
  if (un) {
    const float4 u0 = *(const float4*)(un + k0);
    const float4 u1 = *(const float4*)(un + k0 + 4);
    const float4 a0 = *(const float4*)(wcl + 128 + k0);
    const float4 a1 = *(const float4*)(wcl + 128 + k0 + 4);
    const float4 b0 = *(const float4*)(wcl + 384 + k0);
    const float4 b1 = *(const float4*)(wcl + 384 + k0 + 4);
    s0 += u0.x * a0.x + u0.y * a0.y + u0.z * a0.z + u0.w * a0.w
        + u1.x * a1.x + u1.y * a1.y + u1.z * a1.z + u1.w * a1.w;
    s1 += u0.x * b0.x + u0.y * b0.y + u0.z * b0.z + u0.w * b0.w
        + u1.x * b1.x + u1.y * b1.y + u1.z * b1.z + u1.w * b1.w;
  }
#pragma unroll
  for (int m = 8; m >= 1; m >>= 1) {
    s0 += __shfl_xor(s0, m);
    s1 += __shfl_xor(s1, m);
  }
  if (l16 == 0) {
    s0 += bcl[0]; s1 += bcl[1];
    const float p0 = 1.f / (1.f + expf(-s0));
    const float p1 = 1.f / (1.f + expf(-s1));
    const float mx = fmaxf(p0, p1);
    const float e0 = expf(p0 - mx), e1 = expf(p1 - mx);
    const float inv = 1.f / (e0 + e1);
    o[0] = e0 * inv;
    o[1] = e1 * inv;
  }
}

// ================= Kernel A: leaf gather + up levels 8..4 =================
// grid = 32*16 (batch, level-4 subtree); 512 thr: g = t>>4 (0..31), l16 = t&15.
// ~60 KB LDS -> 2 blocks/CU (pins RA occupancy target at 4 waves/SIMD).
__global__ __launch_bounds__(512, 4) void kA_up(const int* __restrict__ x,
                                                const int* __restrict__ cue,
                                                const float* __restrict__ emb,
                                                const float* __restrict__ Wc,
                                                const float* __restrict__ bc,
                                                float* __restrict__ hw) {
  __shared__ __align__(16) float heap[63 * HB];
  __shared__ __align__(16) float pad[7296];   // unused; pins occupancy via LDS
  const int b = blockIdx.x >> 4, s = blockIdx.x & 15, r = 15 + s;
  const int t = threadIdx.x, g = t >> 4, l16 = t & 15;
  if (t == 0) ((volatile float*)pad)[0] = 0.f;

  float4 w[4][4];
#pragma unroll
  for (int rr = 0; rr < 4; ++rr)
#pragma unroll
    for (int m = 0; m < 4; ++m)
      w[rr][m] = *(const float4*)(Wc + (4 * g + rr) * 256 + l16 * 4 + m * 64);
  const float bias_r = bc[4 * g + (l16 & 3)];

  // leaf features: [emb[x] (126) | one_hot(cue,2)]
  for (int idx = t; idx < 32 * HB; idx += 512) {
    const int j = idx >> 7, k = idx & 127;
    const int gq = ((r + 1) << 5) - 1 + j;     // global leaf node (511..1022)
    float v;
    if (k < 126) v = emb[(long long)x[b * NNODES + gq] * 126 + k];
    else         v = (cue[b * NNODES + gq] == (k - 126)) ? 1.f : 0.f;
    heap[(31 + j) * HB + k] = v;
  }
  __syncthreads();

  up_level16<16, 1>(heap, w, bias_r, g, l16, 0);
  up_level16<8, 1>(heap, w, bias_r, g, l16, 0);
  up_level16<4, 1>(heap, w, bias_r, g, l16, 0);
  up_level16<2, 1>(heap, w, bias_r, g, l16, 0);
  up_level16<1, 1>(heap, w, bias_r, g, l16, 0);

  float4* dst = (float4*)(hw + (size_t)(b * 16 + s) * 31 * HB);
  const float4* src = (const float4*)heap;
  for (int idx = t; idx < 31 * 32; idx += 512) dst[idx] = src[idx];
}

// ================= Kernel B: up 3..0, g_down, down 0..3, classify 0..14 =================
// 1024 thr, one block per batch. Up: rows 128 -> 2 thread-halves on disjoint
// parents. Down: rows 256 -> all threads. >80 KB LDS -> 1 block/CU.
__global__ __launch_bounds__(1024, 4) void kB_mid(const float* __restrict__ Wc,
                                                  const float* __restrict__ bc,
                                                  const float* __restrict__ Wg,
                                                  const float* __restrict__ bg,
                                                  const float* __restrict__ Wd,
                                                  const float* __restrict__ bd,
                                                  const float* __restrict__ Wcl,
                                                  const float* __restrict__ bcl,
                                                  const float* __restrict__ hw,
                                                  float* __restrict__ dw,
                                                  float* __restrict__ out) {
  __shared__ __align__(16) float ub[31 * HB];   // up h, nodes 0..30
  __shared__ __align__(16) float db[31 * HB];   // down, nodes 0..30
  __shared__ __align__(16) float pad[12084];    // unused; pins occupancy via LDS
  __shared__ __align__(16) float wcl[512];
  const int b = blockIdx.x, t = threadIdx.x;
  if (t == 0) ((volatile float*)pad)[0] = 0.f;

  // level-4 h (root of each subtree s) -> ub[15..30]  (float4 staging)
  {
    float4* u4 = (float4*)(ub + 15 * HB);
    for (int idx = t; idx < 16 * 32; idx += 1024) {
      const int s = idx >> 5, k4 = idx & 31;
      u4[idx] = ((const float4*)(hw + (size_t)(b * 16 + s) * 31 * HB))[k4];
    }
  }
  if (t < 512) wcl[t] = Wcl[t];
  __syncthreads();

  // ---- up levels 3..0 (rows 128: g = (t>>4)&31, halves ph on parents) ----
  {
    const int g = (t >> 4) & 31, l16 = t & 15, ph = t >> 9;
    float4 w[4][4];
#pragma unroll
    for (int rr = 0; rr < 4; ++rr)
#pragma unroll
      for (int m = 0; m < 4; ++m)
        w[rr][m] = *(const float4*)(Wc + (4 * g + rr) * 256 + l16 * 4 + m * 64);
    const float bias_r = bc[4 * g + (l16 & 3)];
    up_level16<8, 2>(ub, w, bias_r, g, l16, ph);
    up_level16<4, 2>(ub, w, bias_r, g, l16, ph);
    up_level16<2, 2>(ub, w, bias_r, g, l16, ph);
    up_level16<1, 2>(ub, w, bias_r, g, l16, ph);

    // g_down = sigmoid(Wg @ h_root + bg): 128-wide ctx, k-slices l16*4+64m, m=0..1
    float4 wg[4][2];
#pragma unroll
    for (int rr = 0; rr < 4; ++rr)
#pragma unroll
      for (int m = 0; m < 2; ++m)
        wg[rr][m] = *(const float4*)(Wg + (4 * g + rr) * 128 + l16 * 4 + m * 64);
    float a[4];
#pragma unroll
    for (int v = 0; v < 4; ++v) a[v] = 0.f;
#pragma unroll
    for (int m = 0; m < 2; ++m) {
      const float4 cc = *(const float4*)(ub + l16 * 4 + m * 64);
#pragma unroll
      for (int rr = 0; rr < 4; ++rr) {
        const float4 wv = wg[rr][m];
        a[rr] = fmaf(wv.x, cc.x, fmaf(wv.y, cc.y, fmaf(wv.z, cc.z, fmaf(wv.w, cc.w, a[rr]))));
      }
    }
    float tot = fold4(a, l16);
    tot += __shfl_xor(tot, 4);           // complete the 16-lane sum
    tot += __shfl_xor(tot, 8);
    if (ph == 0 && l16 < 4) {
      const int row = 4 * g + l16;
      db[row] = 1.f / (1.f + expf(-(tot + bg[row])));
    }
    __syncthreads();
  }
  asm volatile("" ::: "memory");  // keep Wd loads from hoisting into the up phase

  // ---- down levels 0..3 (rows 256: g = t>>4) ----
  {
    const int g = t >> 4, l16 = t & 15;
    float4 w[4][4];
#pragma unroll
    for (int rr = 0; rr < 4; ++rr)
#pragma unroll
      for (int m = 0; m < 4; ++m)
        w[rr][m] = *(const float4*)(Wd + (4 * g + rr) * 256 + l16 * 4 + m * 64);
    const float bias_r = bd[4 * g + (l16 & 3)];
    down_level16<1>(db, ub, w, bias_r, g, l16);
    down_level16<2>(db, ub, w, bias_r, g, l16);
    down_level16<4>(db, ub, w, bias_r, g, l16);
    down_level16<8>(db, ub, w, bias_r, g, l16);
  }

  // persist level-4 down (nodes 15..30) for kernel C  (float4)
  {
    const float4* s4 = (const float4*)(db + 15 * HB);
    float4* d4 = (float4*)dw;
    for (int idx = t; idx < 16 * 32; idx += 1024)
      d4[(size_t)b * 16 * 32 + idx] = s4[idx];
  }

  // classify global nodes 0..14 (16 threads per node)
  if (t < 15 * 16) {
    const int m = t >> 4;
    classify16(db + m * HB, ub + m * HB, wcl, bcl,
               out + ((size_t)b * NNODES + m) * 2, t & 15);
  }
}

// ================= Kernel C: down levels 4..8 + classify, 2 subtrees/block =================
// grid = 32*8 (batch, subtree-pair); 1024 thr: g = t>>4 (0..63), l16 = t&15.
// 1 block/CU, single resident round; Wd regs + wcl loaded once, reused.
__global__ __launch_bounds__(1024, 4) void kC_down(const float* __restrict__ Wd,
                                                   const float* __restrict__ bd,
                                                   const float* __restrict__ Wcl,
                                                   const float* __restrict__ bcl,
                                                   const float* __restrict__ hw,
                                                   const float* __restrict__ dw,
                                                   float* __restrict__ out) {
  __shared__ __align__(16) float ub[31 * HB];   // up h, local nodes 0..30
  __shared__ __align__(16) float db[63 * HB];   // down, local nodes 0..62
  __shared__ __align__(16) float pad[7960];     // unused; pins occupancy via LDS
  __shared__ __align__(16) float wcl[512];
  const int b = blockIdx.x >> 3, sp = blockIdx.x & 7;
  const int t = threadIdx.x, g = t >> 4, l16 = t & 15;
  if (t == 0) ((volatile float*)pad)[0] = 0.f;

  float4 w[4][4];
#pragma unroll
  for (int rr = 0; rr < 4; ++rr)
#pragma unroll
    for (int m = 0; m < 4; ++m)
      w[rr][m] = *(const float4*)(Wd + (4 * g + rr) * 256 + l16 * 4 + m * 64);
  const float bias_r = bd[4 * g + (l16 & 3)];
  if (t < 512) wcl[t] = Wcl[t];

  for (int ss = 0; ss < 2; ++ss) {
    const int s = sp * 2 + ss, r = 15 + s;

    // stage this subtree's up h + root down (float4)
    {
      const float4* s4 = (const float4*)(hw + (size_t)(b * 16 + s) * 31 * HB);
      float4* u4 = (float4*)ub;
      for (int idx = t; idx < 31 * 32; idx += 1024) u4[idx] = s4[idx];
      const float4* dv = (const float4*)(dw + (size_t)(b * 16 + s) * HB);
      if (t < 32) ((float4*)db)[t] = dv[t];    // down at subtree root
    }
    __syncthreads();

    down_level16<1>(db, ub, w, bias_r, g, l16);
    down_level16<2>(db, ub, w, bias_r, g, l16);
    down_level16<4>(db, ub, w, bias_r, g, l16);
    down_level16<8>(db, ub, w, bias_r, g, l16);
    down_level16<16>(db, ub, w, bias_r, g, l16);

    // classify local heap nodes 0..62 (16 threads/node); leaves have up = 0
    if (t < 63 * 16) {
      const int m = t >> 4;
      const int lvl = 31 - __clz(m + 1);
      const int j = (m + 1) - (1 << lvl);
      const int gq = ((r + 1) << lvl) - 1 + j;
      classify16(db + m * HB, (m < 31) ? (ub + m * HB) : nullptr, wcl, bcl,
                 out + ((size_t)b * NNODES + gq) * 2, t & 15);
    }
    __syncthreads();   // classify reads db/ub before next subtree overwrites
  }
}

extern "C" void kernel_launch(void* const* d_in, const int* in_sizes, int n_in,
                              void* d_out, int out_size, void* d_ws, size_t ws_size,
                              hipStream_t stream) {
  const int*   x   = (const int*)d_in[0];
  // d_in[1] word_index: identity leaf mapping (leaf j at node 511+j) -- unused
  const int*   cue = (const int*)d_in[2];
  // d_in[3] adj: encodes the same hardcoded heap tree -- unused
  const float* emb = (const float*)d_in[4];
  const float* Wc  = (const float*)d_in[5];
  const float* bc  = (const float*)d_in[6];
  const float* Wd  = (const float*)d_in[7];
  const float* bd  = (const float*)d_in[8];
  const float* Wg  = (const float*)d_in[9];
  const float* bg  = (const float*)d_in[10];
  const float* Wcl = (const float*)d_in[11];
  const float* bcl = (const float*)d_in[12];
  float* out = (float*)d_out;

  float* hw = (float*)d_ws;                       // [B][16][31][128] up h
  float* dw = hw + (size_t)32 * 16 * 31 * 128;    // [B][16][128] level-4 down

  hipLaunchKernelGGL(kA_up,   dim3(512), dim3(512), 0, stream, x, cue, emb, Wc, bc, hw);
  hipLaunchKernelGGL(kB_mid,  dim3(32),  dim3(1024), 0, stream,
                     Wc, bc, Wg, bg, Wd, bd, Wcl, bcl, hw, dw, out);
  hipLaunchKernelGGL(kC_down, dim3(256), dim3(1024), 0, stream,
                     Wd, bd, Wcl, bcl, hw, dw, out);
}

// Round 10
// 76.951 us; speedup vs baseline: 1.0500x; 1.0500x over previous
//
#include <hip/hip_runtime.h>

// TreeRecurrentTagger: B=32, N=1023 nodes (complete heap), HID=128, NCLS=2.
// TWO stream-ordered kernels. Weights in per-thread registers, activations
// in LDS, fp32 VALU.
//
// R3: fit under the RA's 128-VGPR occupancy target. 1853 -> 142.6 µs.
// R5: granule-interleaved k-split + shfl_xor reduce. 142.6 -> 100.2 µs.
// R6/R7: R=4 rows/thread KS=16 + complete 16-lane fold. 100.2 -> 80.6 µs.
// R8: kC 2 subtrees/block — FLAT (80.8): weight re-fetch + 2nd block round
//     were not the cost. Theory revised: kB's 32-block serial middle (12.5%
//     machine util) + kernel boundaries + dw round-trip are the overhead.
// R9: eliminate kB. Every kC block redundantly recomputes the middle
//     (up 3..0, g_down, down 0..3) from hw level-4 roots — 9 stages at full
//     machine parallelism instead of 32 blocks serial. sp==0 block classifies
//     nodes 0..14. dw workspace gone. 2 kernels, 1 boundary.

constexpr int NNODES = 1023;
constexpr int HB = 128;   // HID

// ---- folding cross-lane reduces within 16-lane groups ----
// a[NV] per-lane partials; every value needs the sum over ALL 16 lanes.
__device__ __forceinline__ float fold16(const float* a, int l) {
  float b[8];
#pragma unroll
  for (int u = 0; u < 8; ++u) {
    const float mine = (l & 1) ? a[2 * u + 1] : a[2 * u];
    const float oth  = (l & 1) ? a[2 * u]     : a[2 * u + 1];
    b[u] = mine + __shfl_xor(oth, 1);
  }
  float c[4];
#pragma unroll
  for (int u = 0; u < 4; ++u) {
    const float mine = (l & 2) ? b[2 * u + 1] : b[2 * u];
    const float oth  = (l & 2) ? b[2 * u]     : b[2 * u + 1];
    c[u] = mine + __shfl_xor(oth, 2);
  }
  float d[2];
#pragma unroll
  for (int u = 0; u < 2; ++u) {
    const float mine = (l & 4) ? c[2 * u + 1] : c[2 * u];
    const float oth  = (l & 4) ? c[2 * u]     : c[2 * u + 1];
    d[u] = mine + __shfl_xor(oth, 4);
  }
  const float mine = (l & 8) ? d[1] : d[0];
  const float oth  = (l & 8) ? d[0] : d[1];
  return mine + __shfl_xor(oth, 8);
}

__device__ __forceinline__ float fold8(const float* a, int l) {
  float b[4];
#pragma unroll
  for (int u = 0; u < 4; ++u) {
    const float mine = (l & 1) ? a[2 * u + 1] : a[2 * u];
    const float oth  = (l & 1) ? a[2 * u]     : a[2 * u + 1];
    b[u] = mine + __shfl_xor(oth, 1);
  }
  float c[2];
#pragma unroll
  for (int u = 0; u < 2; ++u) {
    const float mine = (l & 2) ? b[2 * u + 1] : b[2 * u];
    const float oth  = (l & 2) ? b[2 * u]     : b[2 * u + 1];
    c[u] = mine + __shfl_xor(oth, 2);
  }
  const float mine = (l & 4) ? c[1] : c[0];
  const float oth  = (l & 4) ? c[0] : c[1];
  return mine + __shfl_xor(oth, 4);
}

__device__ __forceinline__ float fold4(const float* a, int l) {
  float b[2];
#pragma unroll
  for (int u = 0; u < 2; ++u) {
    const float mine = (l & 1) ? a[2 * u + 1] : a[2 * u];
    const float oth  = (l & 1) ? a[2 * u]     : a[2 * u + 1];
    b[u] = mine + __shfl_xor(oth, 1);
  }
  const float mine = (l & 2) ? b[1] : b[0];
  const float oth  = (l & 2) ? b[0] : b[1];
  return mine + __shfl_xor(oth, 2);
}

// Complete 16-lane total for value v = l16 & (CH*4-1), landing on lane v
// (and duplicates at v+CH*4, ...).
template<int CH>
__device__ __forceinline__ float foldCH(const float (&a)[CH * 4], int l16) {
  if constexpr (CH == 4) {
    return fold16(a, l16);
  } else if constexpr (CH == 2) {
    float t = fold8(a, l16);
    t += __shfl_xor(t, 8);
    return t;
  } else {
    float t = fold4(a, l16);
    t += __shfl_xor(t, 4);
    t += __shfl_xor(t, 8);
    return t;
  }
}

// ---------- up pass: CH parents, out = tanh(Wc @ [h_l, h_r] + bc) ----------
// Thread: row-group g (rows 4g..4g+3), k-lane l16 (k-slice = floats
// l16*4 + 64m + e, m=0..3 of the 256-wide child ctx at node cb+2p).
template<int CH>
__device__ __forceinline__ void up_pass(float* __restrict__ heap, int base, int cb,
                                        int cbase, const float4 (&w)[4][4],
                                        float bias_r, int g, int l16, bool wr) {
  float a[CH * 4];
#pragma unroll
  for (int v = 0; v < CH * 4; ++v) a[v] = 0.f;
#pragma unroll
  for (int p = 0; p < CH; ++p) {
    const float* cp = heap + (cb + 2 * (cbase + p)) * HB + l16 * 4;
#pragma unroll
    for (int m = 0; m < 4; ++m) {
      const float4 cc = *(const float4*)(cp + m * 64);
#pragma unroll
      for (int r = 0; r < 4; ++r) {
        const float4 wv = w[r][m];
        a[p * 4 + r] = fmaf(wv.x, cc.x, fmaf(wv.y, cc.y,
                        fmaf(wv.z, cc.z, fmaf(wv.w, cc.w, a[p * 4 + r]))));
      }
    }
  }
  const float tot = foldCH<CH>(a, l16);
  if (wr && l16 < CH * 4) {
    const int p = l16 >> 2;
    heap[(base + cbase + p) * HB + 4 * g + (l16 & 3)] = tanhf(tot + bias_r);
  }
}

// NH = thread-halves (1: all threads share parents; 2: halves take disjoint parents).
template<int NP, int NH>
__device__ __forceinline__ void up_level16(float* __restrict__ heap,
                                           const float4 (&w)[4][4],
                                           float bias_r, int g, int l16, int ph) {
  constexpr int base = NP - 1, cb = 2 * NP - 1;
  if constexpr (NP >= 4 * NH) {
#pragma unroll
    for (int c0 = 0; c0 < NP; c0 += 4 * NH)
      up_pass<4>(heap, base, cb, c0 + ph * 4, w, bias_r, g, l16, true);
  } else if constexpr (NP * 2 == 4 * NH) {
    up_pass<2>(heap, base, cb, ph * 2, w, bias_r, g, l16, true);
  } else if constexpr (NP == NH) {
    up_pass<1>(heap, base, cb, ph, w, bias_r, g, l16, true);
  } else {  // NP=1, NH=2: both halves compute, half 0 writes
    up_pass<1>(heap, base, cb, 0, w, bias_r, g, l16, ph == 0);
  }
  __syncthreads();
}

// ---------- down pass: ch = tanh(Wd @ [down_p, up_p] + bd) ----------
// ctx k: m=0,1 -> down[l16*4 + 64m]; m=2,3 -> up[l16*4 + 64(m-2)].
// Lane l16 writes (parent cbase+(l16>>2), output row 4g+(l16&3)); row<128 ->
// left child, else right.
template<int CH>
__device__ __forceinline__ void down_pass(float* __restrict__ db,
                                          const float* __restrict__ ub,
                                          int base, int cb, int cbase,
                                          const float4 (&w)[4][4],
                                          float bias_r, int g, int l16) {
  float a[CH * 4];
#pragma unroll
  for (int v = 0; v < CH * 4; ++v) a[v] = 0.f;
#pragma unroll
  for (int p = 0; p < CH; ++p) {
    const float* dp = db + (base + cbase + p) * HB + l16 * 4;
    const float* up = ub + (base + cbase + p) * HB + l16 * 4;
#pragma unroll
    for (int m = 0; m < 4; ++m) {
      const float4 cc = *(const float4*)(((m < 2) ? dp : up) + (m & 1) * 64);
#pragma unroll
      for (int r = 0; r < 4; ++r) {
        const float4 wv = w[r][m];
        a[p * 4 + r] = fmaf(wv.x, cc.x, fmaf(wv.y, cc.y,
                        fmaf(wv.z, cc.z, fmaf(wv.w, cc.w, a[p * 4 + r]))));
      }
    }
  }
  const float tot = foldCH<CH>(a, l16);
  if (l16 < CH * 4) {
    const int p = l16 >> 2;
    const int row = 4 * g + (l16 & 3);     // 0..255
    db[(cb + 2 * (cbase + p) + (row >> 7)) * HB + (row & 127)] = tanhf(tot + bias_r);
  }
}

template<int NP>
__device__ __forceinline__ void down_level16(float* __restrict__ db,
                                             const float* __restrict__ ub,
                                             const float4 (&w)[4][4],
                                             float bias_r, int g, int l16) {
  constexpr int base = NP - 1, cb = 2 * NP - 1;
  if constexpr (NP >= 4) {
#pragma unroll
    for (int c0 = 0; c0 < NP; c0 += 4)
      down_pass<4>(db, ub, base, cb, c0, w, bias_r, g, l16);
  } else {
    down_pass<NP>(db, ub, base, cb, 0, w, bias_r, g, l16);
  }
  __syncthreads();
}

// ---------- classifier, 16 threads/node, float4 loads + shfl reduce ----------
__device__ __forceinline__ void classify16(const float* __restrict__ dn,
                                           const float* __restrict__ un,
                                           const float* __restrict__ wcl,
                                           const float* __restrict__ bcl,
                                           float* __restrict__ o, int l16) {
  const int k0 = l16 * 8;
  float s0, s1;
  {
    const float4 d0 = *(const float4*)(dn + k0);
    const float4 d1 = *(const float4*)(dn + k0 + 4);
    const float4 a0 = *(const float4*)(wcl + k0);
    const float4 a1 = *(const float4*)(wcl + k0 + 4);
    const float4 b0 = *(const float4*)(wcl + 256 + k0);
    const float4 b1 = *(const float4*)(wcl + 256 + k0 + 4);
    s0 = d0.x * a0.x + d0.y * a0.y + d0.z * a0.z + d0.w * a0.w
       + d1.x * a1.x + d1.y * a1.y + d1.z * a1.z + d1.w * a1.w;
    s1 = d0.x * b0.x + d0.y * b0.y + d0.z * b0.z + d0.w * b0.w
       + d1.x * b1.x + d1.y * b1.y + d1.z * b1.z + d1.w * b1.w;
  }
  if (un) {
    const float4 u0 = *(const float4*)(un + k0);
    const float4 u1 = *(const float4*)(un + k0 + 4);
    const float4 a0 = *(const float4*)(wcl + 128 + k0);
    const float4 a1 = *(const float4*)(wcl + 128 + k0 + 4);
    const float4 b0 = *(const float4*)(wcl + 384 + k0);
    const float4 b1 = *(const float4*)(wcl + 384 + k0 + 4);
    s0 += u0.x * a0.x + u0.y * a0.y + u0.z * a0.z + u0.w * a0.w
        + u1.x * a1.x + u1.y * a1.y + u1.z * a1.z + u1.w * a1.w;
    s1 += u0.x * b0.x + u0.y * b0.y + u0.z * b0.z + u0.w * b0.w
        + u1.x * b1.x + u1.y * b1.y + u1.z * b1.z + u1.w * b1.w;
  }
#pragma unroll
  for (int m = 8; m >= 1; m >>= 1) {
    s0 += __shfl_xor(s0, m);
    s1 += __shfl_xor(s1, m);
  }
  if (l16 == 0) {
    s0 += bcl[0]; s1 += bcl[1];
    const float p0 = 1.f / (1.f + expf(-s0));
    const float p1 = 1.f / (1.f + expf(-s1));
    const float mx = fmaxf(p0, p1);
    const float e0 = expf(p0 - mx), e1 = expf(p1 - mx);
    const float inv = 1.f / (e0 + e1);
    o[0] = e0 * inv;
    o[1] = e1 * inv;
  }
}

// ================= Kernel A: leaf gather + up levels 8..4 =================
// grid = 32*16 (batch, level-4 subtree); 512 thr: g = t>>4 (0..31), l16 = t&15.
// ~60 KB LDS -> 2 blocks/CU (pins RA occupancy target at 4 waves/SIMD).
__global__ __launch_bounds__(512, 4) void kA_up(const int* __restrict__ x,
                                                const int* __restrict__ cue,
                                                const float* __restrict__ emb,
                                                const float* __restrict__ Wc,
                                                const float* __restrict__ bc,
                                                float* __restrict__ hw) {
  __shared__ __align__(16) float heap[63 * HB];
  __shared__ __align__(16) float pad[7296];   // unused; pins occupancy via LDS
  const int b = blockIdx.x >> 4, s = blockIdx.x & 15, r = 15 + s;
  const int t = threadIdx.x, g = t >> 4, l16 = t & 15;
  if (t == 0) ((volatile float*)pad)[0] = 0.f;

  float4 w[4][4];
#pragma unroll
  for (int rr = 0; rr < 4; ++rr)
#pragma unroll
    for (int m = 0; m < 4; ++m)
      w[rr][m] = *(const float4*)(Wc + (4 * g + rr) * 256 + l16 * 4 + m * 64);
  const float bias_r = bc[4 * g + (l16 & 3)];

  // leaf features: [emb[x] (126) | one_hot(cue,2)]
  for (int idx = t; idx < 32 * HB; idx += 512) {
    const int j = idx >> 7, k = idx & 127;
    const int gq = ((r + 1) << 5) - 1 + j;     // global leaf node (511..1022)
    float v;
    if (k < 126) v = emb[(long long)x[b * NNODES + gq] * 126 + k];
    else         v = (cue[b * NNODES + gq] == (k - 126)) ? 1.f : 0.f;
    heap[(31 + j) * HB + k] = v;
  }
  __syncthreads();

  up_level16<16, 1>(heap, w, bias_r, g, l16, 0);
  up_level16<8, 1>(heap, w, bias_r, g, l16, 0);
  up_level16<4, 1>(heap, w, bias_r, g, l16, 0);
  up_level16<2, 1>(heap, w, bias_r, g, l16, 0);
  up_level16<1, 1>(heap, w, bias_r, g, l16, 0);

  float4* dst = (float4*)(hw + (size_t)(b * 16 + s) * 31 * HB);
  const float4* src = (const float4*)heap;
  for (int idx = t; idx < 31 * 32; idx += 512) dst[idx] = src[idx];
}

// ========== Kernel C: redundant middle + down levels 4..8 + classify ==========
// grid = 32*8 (batch, subtree-pair); 1024 thr: g = t>>4, l16 = t&15.
// Phase M (all blocks, redundant per batch): stage level-4 roots -> B[15..30],
//   up 3..0 -> B[0..14], g_down -> A[0], down 0..3 -> A[1..30]; sp==0 block
//   classifies nodes 0..14; save this block's 2 root down vectors.
// Phase S (per subtree ss): stage hw slice -> B, root down -> A[0], down
//   5 levels in A[0..62], classify 63 nodes.
__global__ __launch_bounds__(1024, 4) void kC_all(const float* __restrict__ Wc,
                                                  const float* __restrict__ bc,
                                                  const float* __restrict__ Wg,
                                                  const float* __restrict__ bg,
                                                  const float* __restrict__ Wd,
                                                  const float* __restrict__ bd,
                                                  const float* __restrict__ Wcl,
                                                  const float* __restrict__ bcl,
                                                  const float* __restrict__ hw,
                                                  float* __restrict__ out) {
  __shared__ __align__(16) float A[63 * HB];    // mdb (31 rows) then subtree db (63)
  __shared__ __align__(16) float B[31 * HB];    // mub then subtree ub
  __shared__ __align__(16) float rootdn[2 * HB];
  __shared__ __align__(16) float wcl[512];
  __shared__ __align__(16) float pad[7400];     // unused; pins 1 block/CU via LDS
  const int b = blockIdx.x >> 3, sp = blockIdx.x & 7;
  const int t = threadIdx.x, g = t >> 4, l16 = t & 15;
  if (t == 0) ((volatile float*)pad)[0] = 0.f;

  // ---- Phase M staging: level-4 roots (subtree node 0 of each s) -> B[15..30]
  {
    float4* B4 = (float4*)(B + 15 * HB);
    for (int idx = t; idx < 16 * 32; idx += 1024) {
      const int s = idx >> 5, k4 = idx & 31;
      B4[idx] = ((const float4*)(hw + (size_t)(b * 16 + s) * 31 * HB))[k4];
    }
  }
  if (t < 512) wcl[t] = Wcl[t];
  __syncthreads();

  // ---- up levels 3..0 (rows 128: g&31, thread-halves ph on parents) ----
  {
    const int gu = g & 31, ph = t >> 9;
    float4 w[4][4];
#pragma unroll
    for (int rr = 0; rr < 4; ++rr)
#pragma unroll
      for (int m = 0; m < 4; ++m)
        w[rr][m] = *(const float4*)(Wc + (4 * gu + rr) * 256 + l16 * 4 + m * 64);
    const float bias_r = bc[4 * gu + (l16 & 3)];
    up_level16<8, 2>(B, w, bias_r, gu, l16, ph);
    up_level16<4, 2>(B, w, bias_r, gu, l16, ph);
    up_level16<2, 2>(B, w, bias_r, gu, l16, ph);
    up_level16<1, 2>(B, w, bias_r, gu, l16, ph);

    // g_down = sigmoid(Wg @ h_root + bg) -> A[0..127]
    float4 wg[4][2];
#pragma unroll
    for (int rr = 0; rr < 4; ++rr)
#pragma unroll
      for (int m = 0; m < 2; ++m)
        wg[rr][m] = *(const float4*)(Wg + (4 * gu + rr) * 128 + l16 * 4 + m * 64);
    float a[4];
#pragma unroll
    for (int v = 0; v < 4; ++v) a[v] = 0.f;
#pragma unroll
    for (int m = 0; m < 2; ++m) {
      const float4 cc = *(const float4*)(B + l16 * 4 + m * 64);
#pragma unroll
      for (int rr = 0; rr < 4; ++rr) {
        const float4 wv = wg[rr][m];
        a[rr] = fmaf(wv.x, cc.x, fmaf(wv.y, cc.y, fmaf(wv.z, cc.z, fmaf(wv.w, cc.w, a[rr]))));
      }
    }
    float tot = fold4(a, l16);
    tot += __shfl_xor(tot, 4);
    tot += __shfl_xor(tot, 8);
    if (ph == 0 && l16 < 4) {
      const int row = 4 * gu + l16;
      A[row] = 1.f / (1.f + expf(-(tot + bg[row])));
    }
    __syncthreads();
  }
  asm volatile("" ::: "memory");  // keep Wd loads from hoisting into the up phase

  // ---- Wd half... quarter-rows in regs (reused for middle-down AND both subtrees)
  float4 w[4][4];
#pragma unroll
  for (int rr = 0; rr < 4; ++rr)
#pragma unroll
    for (int m = 0; m < 4; ++m)
      w[rr][m] = *(const float4*)(Wd + (4 * g + rr) * 256 + l16 * 4 + m * 64);
  const float bias_r = bd[4 * g + (l16 & 3)];

  // ---- middle down levels 0..3: A[0] -> A[1..30]
  down_level16<1>(A, B, w, bias_r, g, l16);
  down_level16<2>(A, B, w, bias_r, g, l16);
  down_level16<4>(A, B, w, bias_r, g, l16);
  down_level16<8>(A, B, w, bias_r, g, l16);

  // classify global nodes 0..14 (only one block per batch)
  if (sp == 0 && t < 15 * 16) {
    const int m = t >> 4;
    classify16(A + m * HB, B + m * HB, wcl, bcl,
               out + ((size_t)b * NNODES + m) * 2, l16);
  }
  // save this block's two subtree-root down vectors before reusing A
  if (t < 256) rootdn[t] = A[(15 + sp * 2 + (t >> 7)) * HB + (t & 127)];
  __syncthreads();

  // ---- Phase S: two subtrees ----
  for (int ss = 0; ss < 2; ++ss) {
    const int s = sp * 2 + ss, r = 15 + s;

    {
      const float4* s4 = (const float4*)(hw + (size_t)(b * 16 + s) * 31 * HB);
      float4* B4 = (float4*)B;
      for (int idx = t; idx < 31 * 32; idx += 1024) B4[idx] = s4[idx];
      if (t < HB) A[t] = rootdn[ss * HB + t];   // down at subtree root
    }
    __syncthreads();

    down_level16<1>(A, B, w, bias_r, g, l16);
    down_level16<2>(A, B, w, bias_r, g, l16);
    down_level16<4>(A, B, w, bias_r, g, l16);
    down_level16<8>(A, B, w, bias_r, g, l16);
    down_level16<16>(A, B, w, bias_r, g, l16);

    // classify local heap nodes 0..62 (16 threads/node); leaves have up = 0
    if (t < 63 * 16) {
      const int m = t >> 4;
      const int lvl = 31 - __clz(m + 1);
      const int j = (m + 1) - (1 << lvl);
      const int gq = ((r + 1) << lvl) - 1 + j;
      classify16(A + m * HB, (m < 31) ? (B + m * HB) : nullptr, wcl, bcl,
                 out + ((size_t)b * NNODES + gq) * 2, l16);
    }
    __syncthreads();   // classify reads A/B before next subtree overwrites
  }
}

extern "C" void kernel_launch(void* const* d_in, const int* in_sizes, int n_in,
                              void* d_out, int out_size, void* d_ws, size_t ws_size,
                              hipStream_t stream) {
  const int*   x   = (const int*)d_in[0];
  // d_in[1] word_index: identity leaf mapping (leaf j at node 511+j) -- unused
  const int*   cue = (const int*)d_in[2];
  // d_in[3] adj: encodes the same hardcoded heap tree -- unused
  const float* emb = (const float*)d_in[4];
  const float* Wc  = (const float*)d_in[5];
  const float* bc  = (const float*)d_in[6];
  const float* Wd  = (const float*)d_in[7];
  const float* bd  = (const float*)d_in[8];
  const float* Wg  = (const float*)d_in[9];
  const float* bg  = (const float*)d_in[10];
  const float* Wcl = (const float*)d_in[11];
  const float* bcl = (const float*)d_in[12];
  float* out = (float*)d_out;

  float* hw = (float*)d_ws;                       // [B][16][31][128] up h

  hipLaunchKernelGGL(kA_up,  dim3(512), dim3(512), 0, stream, x, cue, emb, Wc, bc, hw);
  hipLaunchKernelGGL(kC_all, dim3(256), dim3(1024), 0, stream,
                     Wc, bc, Wg, bg, Wd, bd, Wcl, bcl, hw, out);
}